// Round 2
// baseline (510.984 us; speedup 1.0000x reference)
//
#include <hip/hip_runtime.h>

// Problem: B=64, T=2048, D=512, H=64, K=3, S=3, PAD=1
#define T_LEN 2048
#define D_DIM 512
#define B_SZ  64
#define T1_LEN 683     // ceil(2048/3)
#define NSEL  32
#define KTOT  1536     // 3*512 reduction dim of conv1-as-GEMM
#define BK    64       // K chunk per iteration
#define TILE_T1 96     // t1 tile per block; 8 tiles cover 768 >= 683
#define NTILES 8
#define NITER (KTOT / BK)   // 24

typedef __attribute__((ext_vector_type(8))) short bf16x8;
typedef __attribute__((ext_vector_type(4))) float f32x4;

// Workspace layout (bytes)
constexpr size_t OFF_WHI = 0;         // 128*1536 bf16 = 393216 B (pre-swizzled tile layout)
constexpr size_t OFF_WLO = 393216;    // 393216 B
constexpr size_t OFF_EST = 786432;    // 64 floats
constexpr size_t OFF_SEL = 786944;    // 32 ints

__device__ inline unsigned bf16_rne(float x) {
    unsigned u = __float_as_uint(x);
    return (u + 0x7FFFu + ((u >> 16) & 1u)) >> 16;
}

// cheap round-half-up bf16 (2 ops); residual is captured by the lo term,
// so hi rounding mode does not affect the 3-term product error bound.
__device__ inline unsigned bf16_rhu(float x) {
    return (__float_as_uint(x) + 0x8000u) >> 16;
}

// ---------------------------------------------------------------------------
// Pack w1[c][d][k] -> whi/wlo in conv1's STAGING layout (pre-swizzled):
//   addr = k0blk*8192 + row*64 + (c8s*8 + e),  where row = c (channel),
//   c8  = c8s ^ (row&7),  kappa = k0blk*64 + c8*8 + e,  kappa = k*512 + d.
// conv1's A-stage then becomes a contiguous int4 copy and the MFMA-phase
// read (ch ^ (row&7)) un-swizzles exactly as before.
// Also zeroes est_raw (runs before conv1 in stream order every launch).
__global__ __launch_bounds__(256) void pack_w1_split(const float* __restrict__ w1,
                                                     unsigned short* __restrict__ whi,
                                                     unsigned short* __restrict__ wlo,
                                                     float* __restrict__ est_raw) {
    if (blockIdx.x == 0 && threadIdx.x < 64) est_raw[threadIdx.x] = 0.f;
    int idx = blockIdx.x * 256 + threadIdx.x;   // 768 blocks * 256 = 196608 exact
    int k0blk = idx >> 13;          // /8192
    int rem   = idx & 8191;
    int row   = rem >> 6;           // channel c, 0..127
    int col   = rem & 63;
    int c8s   = col >> 3;
    int e     = col & 7;
    int c8    = c8s ^ (row & 7);
    int kap   = (k0blk << 6) + (c8 << 3) + e;   // k*512 + d
    int k = kap >> 9, d = kap & 511;
    float v = w1[row * 1536 + d * 3 + k];
    unsigned hb = bf16_rne(v);                  // weights: keep full RNE (one-time)
    float hf = __uint_as_float(hb << 16);
    whi[idx] = (unsigned short)hb;
    wlo[idx] = (unsigned short)bf16_rne(v - hf);
}

// ---------------------------------------------------------------------------
// conv1 (GEMM via 3-term split-bf16 MFMA) + bias + pair-maxpool + mod-3
// weighted reduction -> atomicAdd(est_raw[b]).
// Block: batch b, 96-wide t1 tile, all 128 channels. 4 waves, each owns a
// 64c x 48t1 quadrant = 4x3 frags of 16x16 (MFMA 16x16x32 bf16).
// v2: software-pipelined (T14): global loads for tile t+1 issued into regs
// BEFORE the MFMA phase of tile t; split+LDS-write happen after the
// post-MFMA barrier. HBM latency hides under MFMA; split uses cheap
// round-half-up (7 ops/elem vs 13).
// v3: fix A-stage chunk base (1024 int4 per 16KB K-chunk, not 512).
__global__ __launch_bounds__(256, 2) void conv1_mfma(
        const float* __restrict__ x,
        const unsigned short* __restrict__ whi,
        const unsigned short* __restrict__ wlo,
        const float* __restrict__ b1,
        const float* __restrict__ w2,
        float* __restrict__ est_raw) {
    __shared__ __align__(16) unsigned short Ahi[128 * 64];  // 16 KB
    __shared__ __align__(16) unsigned short Alo[128 * 64];
    __shared__ __align__(16) unsigned short Bhi[96 * 64];   // 12 KB
    __shared__ __align__(16) unsigned short Blo[96 * 64];
    __shared__ float b1s[128];
    __shared__ float w2s[192];
    __shared__ float red[256];

    const int tid  = threadIdx.x;
    const int lane = tid & 63;
    const int w    = tid >> 6;
    const int b    = blockIdx.y;
    const int t1g0 = blockIdx.x * TILE_T1;

    if (tid < 128) b1s[tid] = b1[tid];
    if (tid < 192) w2s[tid] = w2[tid];

    const float* xb = x + (size_t)b * (T_LEN * (size_t)D_DIM);

    const int l15  = lane & 15;
    const int quad = lane >> 4;
    const int c0w  = (w >> 1) * 64;   // c quadrant
    const int t0w  = (w & 1) * 48;    // t1 quadrant

    int offA[4], swA[4];
    #pragma unroll
    for (int mi = 0; mi < 4; ++mi) { int r = c0w + mi * 16 + l15; offA[mi] = r * 64; swA[mi] = r & 7; }
    int offB[3], swB[3];
    #pragma unroll
    for (int ni = 0; ni < 3; ++ni) { int r = t0w + ni * 16 + l15; offB[ni] = r * 64; swB[ni] = r & 7; }

    // B staging per-thread constants (3 ids/thread, 8 fp32 each)
    int bdst[3], gb[3], bok[3];
    #pragma unroll
    for (int q = 0; q < 3; ++q) {
        int id = tid + 256 * q;               // 0..767
        int row = id >> 3, c8 = id & 7;
        int t1abs = t1g0 + row;
        bok[q]  = (t1abs < T1_LEN);
        gb[q]   = 1536 * t1abs + c8 * 8 - 512;
        bdst[q] = row * 64 + ((c8 ^ (row & 7)) << 3);
    }

    f32x4 acc[4][3];
    #pragma unroll
    for (int mi = 0; mi < 4; ++mi)
        #pragma unroll
        for (int ni = 0; ni < 3; ++ni) acc[mi][ni] = (f32x4){0.f, 0.f, 0.f, 0.f};

    // staging registers (prefetch): A = 8 int4, B = 6 float4
    int4  arh[4], arl[4];
    float4 br[6];

    auto load_stage = [&](int k0) {
        // A: contiguous copy of this K-chunk's pre-swizzled 16 KB (x2 for lo).
        // One K-chunk = 128 rows * 64 halves = 8192 halves = 1024 int4.
        const int4* ph = (const int4*)(whi) + (k0 >> 6) * 1024 + tid;
        const int4* pl = (const int4*)(wlo) + (k0 >> 6) * 1024 + tid;
        #pragma unroll
        for (int q = 0; q < 4; ++q) arh[q] = ph[q * 256];
        #pragma unroll
        for (int q = 0; q < 4; ++q) arl[q] = pl[q * 256];
        // B: fp32 x rows
        #pragma unroll
        for (int q = 0; q < 3; ++q) {
            int g = gb[q] + k0;
            float4 z = make_float4(0.f, 0.f, 0.f, 0.f);
            if (bok[q] && g >= 0) {
                br[2 * q]     = *(const float4*)(xb + g);
                br[2 * q + 1] = *(const float4*)(xb + g + 4);
            } else {
                br[2 * q] = z; br[2 * q + 1] = z;
            }
        }
    };

    auto write_stage = [&]() {
        #pragma unroll
        for (int q = 0; q < 4; ++q) ((int4*)Ahi)[tid + q * 256] = arh[q];
        #pragma unroll
        for (int q = 0; q < 4; ++q) ((int4*)Alo)[tid + q * 256] = arl[q];
        #pragma unroll
        for (int q = 0; q < 3; ++q) {
            float fv[8] = {br[2*q].x, br[2*q].y, br[2*q].z, br[2*q].w,
                           br[2*q+1].x, br[2*q+1].y, br[2*q+1].z, br[2*q+1].w};
            unsigned hp[4], lp[4];
            #pragma unroll
            for (int e = 0; e < 4; ++e) {
                unsigned h0 = bf16_rhu(fv[2 * e]);
                unsigned h1 = bf16_rhu(fv[2 * e + 1]);
                float r0 = fv[2 * e]     - __uint_as_float(h0 << 16);
                float r1 = fv[2 * e + 1] - __uint_as_float(h1 << 16);
                unsigned l0 = bf16_rhu(r0);
                unsigned l1 = bf16_rhu(r1);
                hp[e] = h0 | (h1 << 16);
                lp[e] = l0 | (l1 << 16);
            }
            *(int4*)(Bhi + bdst[q]) = make_int4(hp[0], hp[1], hp[2], hp[3]);
            *(int4*)(Blo + bdst[q]) = make_int4(lp[0], lp[1], lp[2], lp[3]);
        }
    };

    // ---- pipelined main loop:
    //   [write LDS(t); (loads t+1 already in flight)] barrier
    //   MFMA(t)  (overlaps with loads t+1)            barrier
    load_stage(0);
    write_stage();
    __syncthreads();

    for (int it = 0; it < NITER; ++it) {
        if (it < NITER - 1) load_stage((it + 1) * BK);

        #pragma unroll
        for (int ks = 0; ks < 2; ++ks) {
            const int ch = ks * 4 + quad;
            bf16x8 ah[4], al[4], bh[3], bl[3];
            #pragma unroll
            for (int mi = 0; mi < 4; ++mi) {
                int o = offA[mi] + ((ch ^ swA[mi]) << 3);
                ah[mi] = *(const bf16x8*)(Ahi + o);
                al[mi] = *(const bf16x8*)(Alo + o);
            }
            #pragma unroll
            for (int ni = 0; ni < 3; ++ni) {
                int o = offB[ni] + ((ch ^ swB[ni]) << 3);
                bh[ni] = *(const bf16x8*)(Bhi + o);
                bl[ni] = *(const bf16x8*)(Blo + o);
            }
            #pragma unroll
            for (int mi = 0; mi < 4; ++mi)
                #pragma unroll
                for (int ni = 0; ni < 3; ++ni) {
                    acc[mi][ni] = __builtin_amdgcn_mfma_f32_16x16x32_bf16(ah[mi], bh[ni], acc[mi][ni], 0, 0, 0);
                    acc[mi][ni] = __builtin_amdgcn_mfma_f32_16x16x32_bf16(ah[mi], bl[ni], acc[mi][ni], 0, 0, 0);
                    acc[mi][ni] = __builtin_amdgcn_mfma_f32_16x16x32_bf16(al[mi], bh[ni], acc[mi][ni], 0, 0, 0);
                }
        }
        __syncthreads();           // all waves done reading tile t
        if (it < NITER - 1) {
            write_stage();         // write tile t+1 (waits vmcnt on staging regs)
            __syncthreads();       // tile t+1 visible
        }
    }

    // ---- epilogue: bias + pair-maxpool (adjacent regs) + mod-3 w2 weighting
    // est contribution: sum_t2 s[b,t2] = 228*b2 + sum over (j,t1) of
    // hm[j,t1] * w2[j][(t1+1)%3]
    float contrib = 0.f;
    #pragma unroll
    for (int mi = 0; mi < 4; ++mi) {
        const int cbase = c0w + mi * 16 + (quad << 2);   // D row = quad*4 + reg
        const float bb0 = b1s[cbase], bb1 = b1s[cbase + 1];
        const float bb2 = b1s[cbase + 2], bb3 = b1s[cbase + 3];
        const int j0 = cbase >> 1;
        #pragma unroll
        for (int ni = 0; ni < 3; ++ni) {
            const int t1 = t1g0 + t0w + ni * 16 + l15;   // D col = lane&15
            if (t1 < T1_LEN) {
                float p0 = fmaxf(acc[mi][ni][0] + bb0, acc[mi][ni][1] + bb1);
                float p1 = fmaxf(acc[mi][ni][2] + bb2, acc[mi][ni][3] + bb3);
                int r = (t1 + 1) % 3;
                contrib += p0 * w2s[j0 * 3 + r] + p1 * w2s[(j0 + 1) * 3 + r];
            }
        }
    }
    red[tid] = contrib;
    __syncthreads();
    for (int off = 128; off > 0; off >>= 1) {
        if (tid < off) red[tid] += red[tid + off];
        __syncthreads();
    }
    if (tid == 0) atomicAdd(est_raw + b, red[0]);
}

// ---------------------------------------------------------------------------
// Top-32 of 64 (ties -> lower index), ascending compaction; writes sel idx
// and sel_lens (as float, tail of d_out).
__global__ void select_k(const float* __restrict__ est_raw,
                         const float* __restrict__ b2,
                         const int* __restrict__ seq_lens,
                         int* __restrict__ sel,
                         float* __restrict__ out_lens) {
    const int i = threadIdx.x;   // 64 threads = 1 wave
    __shared__ float e[64];
    const int L  = seq_lens[i];
    const int sl = ((L + 2) / 3 + 2) / 3;
    const float ei = (est_raw[i] + 228.0f * b2[0]) / (float)sl;  // = sum/sl
    e[i] = ei;
    __syncthreads();
    int rank = 0;
    for (int j = 0; j < 64; ++j) {
        float ej = e[j];
        rank += (ej > ei) || (ej == ei && j < i);
    }
    const bool selq = rank < NSEL;
    const unsigned long long m = __ballot(selq);
    if (selq) {
        int pos = __popcll(m & ((1ull << i) - 1ull));
        sel[pos] = i;
        out_lens[pos] = (float)L;
    }
}

// ---------------------------------------------------------------------------
__global__ __launch_bounds__(256) void gather_rows(const float* __restrict__ x,
                                                   const int* __restrict__ sel,
                                                   float* __restrict__ out,
                                                   int n4row) {
    const int i = blockIdx.y;
    const int v = blockIdx.x * 256 + threadIdx.x;
    if (v < n4row) {
        const int src = sel[i];
        const float4* xs = (const float4*)(x + (size_t)src * T_LEN * D_DIM);
        float4* od = (float4*)(out + (size_t)i * ((size_t)n4row * 4));
        od[v] = xs[v];
    }
}

// ---------------------------------------------------------------------------
extern "C" void kernel_launch(void* const* d_in, const int* in_sizes, int n_in,
                              void* d_out, int out_size, void* d_ws, size_t ws_size,
                              hipStream_t stream) {
    const float* x        = (const float*)d_in[0];
    const int*   seq_lens = (const int*)  d_in[1];
    const float* w1       = (const float*)d_in[2];
    const float* b1       = (const float*)d_in[3];
    const float* w2       = (const float*)d_in[4];
    const float* b2       = (const float*)d_in[5];
    float* out = (float*)d_out;

    char* ws = (char*)d_ws;
    unsigned short* whi = (unsigned short*)(ws + OFF_WHI);
    unsigned short* wlo = (unsigned short*)(ws + OFF_WLO);
    float* est_raw = (float*)(ws + OFF_EST);
    int*   sel     = (int*)  (ws + OFF_SEL);

    const int max_time = (out_size - NSEL) / (NSEL * D_DIM);

    pack_w1_split<<<768, 256, 0, stream>>>(w1, whi, wlo, est_raw);
    conv1_mfma<<<dim3(NTILES, B_SZ), 256, 0, stream>>>(x, whi, wlo, b1, w2, est_raw);
    select_k<<<1, 64, 0, stream>>>(est_raw, b2, seq_lens, sel,
                                   out + (size_t)NSEL * max_time * D_DIM);
    const int n4row = max_time * (D_DIM / 4);
    gather_rows<<<dim3((n4row + 255) / 256, NSEL), 256, 0, stream>>>(x, sel, out, n4row);
}

// Round 3
// 444.084 us; speedup vs baseline: 1.1506x; 1.1506x over previous
//
#include <hip/hip_runtime.h>

// Problem: B=64, T=2048, D=512, H=64, K=3, S=3, PAD=1
#define T_LEN 2048
#define D_DIM 512
#define B_SZ  64
#define T1_LEN 683     // ceil(2048/3)
#define NSEL  32
#define KTOT  1536     // 3*512 reduction dim of conv1-as-GEMM
#define BK    64       // K chunk per iteration
#define TILE_T1 96     // t1 tile per block; 8 tiles cover 768 >= 683
#define NTILES 8
#define NITER (KTOT / BK)   // 24

typedef __attribute__((ext_vector_type(8))) short bf16x8;
typedef __attribute__((ext_vector_type(4))) float f32x4;

// Workspace layout (bytes)
constexpr size_t OFF_WHI = 0;         // 128*1536 bf16 = 393216 B (pre-swizzled tile layout)
constexpr size_t OFF_WLO = 393216;    // 393216 B
constexpr size_t OFF_EST = 786432;    // 64 floats
constexpr size_t OFF_SEL = 786944;    // 32 ints

__device__ inline unsigned bf16_rne(float x) {
    unsigned u = __float_as_uint(x);
    return (u + 0x7FFFu + ((u >> 16) & 1u)) >> 16;
}

// async global->LDS, 16B per lane. LDS dest must be linear in lane order
// (wave-uniform base + lane*16) — our pre-swizzled A staging layout is
// exactly that, so no VGPR roundtrip and no ds_write for the A tile.
__device__ __forceinline__ void gload_lds16(const void* g, void* l) {
    __builtin_amdgcn_global_load_lds(
        (const __attribute__((address_space(1))) unsigned int*)g,
        (__attribute__((address_space(3))) unsigned int*)l,
        16, 0, 0);
}

// ---------------------------------------------------------------------------
// Pack w1[c][d][k] -> whi/wlo in conv1's STAGING layout (pre-swizzled):
//   addr = k0blk*8192 + row*64 + (c8s*8 + e),  where row = c (channel),
//   c8  = c8s ^ (row&7),  kappa = k0blk*64 + c8*8 + e,  kappa = k*512 + d.
// conv1's A-stage is then a contiguous lane-linear copy (global_load_lds)
// and the MFMA-phase read (ch ^ (row&7)) un-swizzles exactly.
// Also zeroes est_raw (runs before conv1 in stream order every launch).
__global__ __launch_bounds__(256) void pack_w1_split(const float* __restrict__ w1,
                                                     unsigned short* __restrict__ whi,
                                                     unsigned short* __restrict__ wlo,
                                                     float* __restrict__ est_raw) {
    if (blockIdx.x == 0 && threadIdx.x < 64) est_raw[threadIdx.x] = 0.f;
    int idx = blockIdx.x * 256 + threadIdx.x;   // 768 blocks * 256 = 196608 exact
    int k0blk = idx >> 13;          // /8192
    int rem   = idx & 8191;
    int row   = rem >> 6;           // channel c, 0..127
    int col   = rem & 63;
    int c8s   = col >> 3;
    int e     = col & 7;
    int c8    = c8s ^ (row & 7);
    int kap   = (k0blk << 6) + (c8 << 3) + e;   // k*512 + d
    int k = kap >> 9, d = kap & 511;
    float v = w1[row * 1536 + d * 3 + k];
    unsigned hb = bf16_rne(v);                  // weights: keep full RNE (one-time)
    float hf = __uint_as_float(hb << 16);
    whi[idx] = (unsigned short)hb;
    wlo[idx] = (unsigned short)bf16_rne(v - hf);
}

// ---------------------------------------------------------------------------
// conv1 (GEMM via 3-term split-bf16 MFMA) + bias + pair-maxpool + mod-3
// weighted reduction -> atomicAdd(est_raw[b]).
// Block: batch b, 96-wide t1 tile, all 128 channels. 4 waves, each owns a
// 64c x 48t1 quadrant = 4x3 frags of 16x16 (MFMA 16x16x32 bf16).
// v4: scratch-spill fix. A-tile staged via global_load_lds (zero staging
// VGPRs, async to the barrier). B staged load->split->ds_write within one
// phase (no cross-MFMA register liveness; no lambdas). Split uses
// truncation-hi via v_perm_b32 pack (3 VALU/elem): hi = trunc16(f),
// residual r = f - hi is EXACT in fp32, lo = trunc16(r); total product
// error ~2^-16 relative — far below top-32 selection margins.
__global__ __launch_bounds__(256, 2) void conv1_mfma(
        const float* __restrict__ x,
        const unsigned short* __restrict__ whi,
        const unsigned short* __restrict__ wlo,
        const float* __restrict__ b1,
        const float* __restrict__ w2,
        float* __restrict__ est_raw) {
    __shared__ __align__(16) unsigned short Ahi[128 * 64];  // 16 KB
    __shared__ __align__(16) unsigned short Alo[128 * 64];
    __shared__ __align__(16) unsigned short Bhi[96 * 64];   // 12 KB
    __shared__ __align__(16) unsigned short Blo[96 * 64];
    __shared__ float b1s[128];
    __shared__ float w2s[192];
    __shared__ float red[256];

    const int tid  = threadIdx.x;
    const int lane = tid & 63;
    const int w    = tid >> 6;
    const int b    = blockIdx.y;
    const int t1g0 = blockIdx.x * TILE_T1;

    if (tid < 128) b1s[tid] = b1[tid];
    if (tid < 192) w2s[tid] = w2[tid];

    const float* xb = x + (size_t)b * (T_LEN * (size_t)D_DIM);

    const int l15  = lane & 15;
    const int quad = lane >> 4;
    const int c0w  = (w >> 1) * 64;   // c quadrant
    const int t0w  = (w & 1) * 48;    // t1 quadrant

    int offA[4], swA[4];
    #pragma unroll
    for (int mi = 0; mi < 4; ++mi) { int r = c0w + mi * 16 + l15; offA[mi] = r * 64; swA[mi] = r & 7; }
    int offB[3], swB[3];
    #pragma unroll
    for (int ni = 0; ni < 3; ++ni) { int r = t0w + ni * 16 + l15; offB[ni] = r * 64; swB[ni] = r & 7; }

    // B staging per-thread constants (3 ids/thread, 8 fp32 each)
    int bdst[3], gb[3], bok[3];
    #pragma unroll
    for (int q = 0; q < 3; ++q) {
        int id = tid + 256 * q;               // 0..767
        int row = id >> 3, c8 = id & 7;
        int t1abs = t1g0 + row;
        bok[q]  = (t1abs < T1_LEN);
        gb[q]   = 1536 * t1abs + c8 * 8 - 512;
        bdst[q] = row * 64 + ((c8 ^ (row & 7)) << 3);
    }

    f32x4 acc[4][3];
    #pragma unroll
    for (int mi = 0; mi < 4; ++mi)
        #pragma unroll
        for (int ni = 0; ni < 3; ++ni) acc[mi][ni] = (f32x4){0.f, 0.f, 0.f, 0.f};

    for (int it = 0; it < NITER; ++it) {
        const int k0 = it * BK;

        // ---- B global loads first (oldest in vmcnt queue: the split's
        // implicit wait retires them without draining the A lds-loads)
        float4 bv0 = make_float4(0.f,0.f,0.f,0.f), bv1 = bv0, bv2 = bv0,
               bv3 = bv0, bv4 = bv0, bv5 = bv0;
        {
            int g0 = gb[0] + k0, g1 = gb[1] + k0, g2 = gb[2] + k0;
            if (bok[0] && g0 >= 0) { bv0 = *(const float4*)(xb + g0); bv1 = *(const float4*)(xb + g0 + 4); }
            if (bok[1] && g1 >= 0) { bv2 = *(const float4*)(xb + g1); bv3 = *(const float4*)(xb + g1 + 4); }
            if (bok[2] && g2 >= 0) { bv4 = *(const float4*)(xb + g2); bv5 = *(const float4*)(xb + g2 + 4); }
        }

        // ---- A: async global->LDS (8 x 16B per thread; lane-linear dest)
        {
            const unsigned short* sH = whi + it * 8192 + tid * 8;
            const unsigned short* sL = wlo + it * 8192 + tid * 8;
            unsigned short* dH = Ahi + tid * 8;
            unsigned short* dL = Alo + tid * 8;
            #pragma unroll
            for (int s = 0; s < 4; ++s) {
                gload_lds16(sH + s * 2048, dH + s * 2048);
                gload_lds16(sL + s * 2048, dL + s * 2048);
            }
        }

        // ---- B split (trunc-hi perm pack + exact residual) + LDS write
        #pragma unroll
        for (int q = 0; q < 3; ++q) {
            float4 va = (q == 0) ? bv0 : (q == 1) ? bv2 : bv4;
            float4 vb = (q == 0) ? bv1 : (q == 1) ? bv3 : bv5;
            unsigned f0 = __float_as_uint(va.x), f1 = __float_as_uint(va.y);
            unsigned f2 = __float_as_uint(va.z), f3 = __float_as_uint(va.w);
            unsigned f4 = __float_as_uint(vb.x), f5 = __float_as_uint(vb.y);
            unsigned f6 = __float_as_uint(vb.z), f7 = __float_as_uint(vb.w);
            unsigned hp0 = __builtin_amdgcn_perm(f1, f0, 0x07060302u);
            unsigned hp1 = __builtin_amdgcn_perm(f3, f2, 0x07060302u);
            unsigned hp2 = __builtin_amdgcn_perm(f5, f4, 0x07060302u);
            unsigned hp3 = __builtin_amdgcn_perm(f7, f6, 0x07060302u);
            float r0 = va.x - __uint_as_float(f0 & 0xFFFF0000u);
            float r1 = va.y - __uint_as_float(f1 & 0xFFFF0000u);
            float r2 = va.z - __uint_as_float(f2 & 0xFFFF0000u);
            float r3 = va.w - __uint_as_float(f3 & 0xFFFF0000u);
            float r4 = vb.x - __uint_as_float(f4 & 0xFFFF0000u);
            float r5 = vb.y - __uint_as_float(f5 & 0xFFFF0000u);
            float r6 = vb.z - __uint_as_float(f6 & 0xFFFF0000u);
            float r7 = vb.w - __uint_as_float(f7 & 0xFFFF0000u);
            unsigned lp0 = __builtin_amdgcn_perm(__float_as_uint(r1), __float_as_uint(r0), 0x07060302u);
            unsigned lp1 = __builtin_amdgcn_perm(__float_as_uint(r3), __float_as_uint(r2), 0x07060302u);
            unsigned lp2 = __builtin_amdgcn_perm(__float_as_uint(r5), __float_as_uint(r4), 0x07060302u);
            unsigned lp3 = __builtin_amdgcn_perm(__float_as_uint(r7), __float_as_uint(r6), 0x07060302u);
            *(int4*)(Bhi + bdst[q]) = make_int4(hp0, hp1, hp2, hp3);
            *(int4*)(Blo + bdst[q]) = make_int4(lp0, lp1, lp2, lp3);
        }
        __syncthreads();   // drains vmcnt(0) lgkmcnt(0): A lds-loads + B writes visible

        #pragma unroll
        for (int ks = 0; ks < 2; ++ks) {
            const int ch = ks * 4 + quad;
            bf16x8 ah[4], al[4], bh[3], bl[3];
            #pragma unroll
            for (int mi = 0; mi < 4; ++mi) {
                int o = offA[mi] + ((ch ^ swA[mi]) << 3);
                ah[mi] = *(const bf16x8*)(Ahi + o);
                al[mi] = *(const bf16x8*)(Alo + o);
            }
            #pragma unroll
            for (int ni = 0; ni < 3; ++ni) {
                int o = offB[ni] + ((ch ^ swB[ni]) << 3);
                bh[ni] = *(const bf16x8*)(Bhi + o);
                bl[ni] = *(const bf16x8*)(Blo + o);
            }
            #pragma unroll
            for (int mi = 0; mi < 4; ++mi)
                #pragma unroll
                for (int ni = 0; ni < 3; ++ni) {
                    acc[mi][ni] = __builtin_amdgcn_mfma_f32_16x16x32_bf16(ah[mi], bh[ni], acc[mi][ni], 0, 0, 0);
                    acc[mi][ni] = __builtin_amdgcn_mfma_f32_16x16x32_bf16(ah[mi], bl[ni], acc[mi][ni], 0, 0, 0);
                    acc[mi][ni] = __builtin_amdgcn_mfma_f32_16x16x32_bf16(al[mi], bh[ni], acc[mi][ni], 0, 0, 0);
                }
        }
        __syncthreads();   // all waves done reading tile t before restage
    }

    // ---- epilogue: bias + pair-maxpool (adjacent regs) + mod-3 w2 weighting
    // est contribution: sum_t2 s[b,t2] = 228*b2 + sum over (j,t1) of
    // hm[j,t1] * w2[j][(t1+1)%3]
    float contrib = 0.f;
    #pragma unroll
    for (int mi = 0; mi < 4; ++mi) {
        const int cbase = c0w + mi * 16 + (quad << 2);   // D row = quad*4 + reg
        const float bb0 = b1s[cbase], bb1 = b1s[cbase + 1];
        const float bb2 = b1s[cbase + 2], bb3 = b1s[cbase + 3];
        const int j0 = cbase >> 1;
        #pragma unroll
        for (int ni = 0; ni < 3; ++ni) {
            const int t1 = t1g0 + t0w + ni * 16 + l15;   // D col = lane&15
            if (t1 < T1_LEN) {
                float p0 = fmaxf(acc[mi][ni][0] + bb0, acc[mi][ni][1] + bb1);
                float p1 = fmaxf(acc[mi][ni][2] + bb2, acc[mi][ni][3] + bb3);
                int r = (t1 + 1) % 3;
                contrib += p0 * w2s[j0 * 3 + r] + p1 * w2s[(j0 + 1) * 3 + r];
            }
        }
    }
    red[tid] = contrib;
    __syncthreads();
    for (int off = 128; off > 0; off >>= 1) {
        if (tid < off) red[tid] += red[tid + off];
        __syncthreads();
    }
    if (tid == 0) atomicAdd(est_raw + b, red[0]);
}

// ---------------------------------------------------------------------------
// Top-32 of 64 (ties -> lower index), ascending compaction; writes sel idx
// and sel_lens (as float, tail of d_out).
__global__ void select_k(const float* __restrict__ est_raw,
                         const float* __restrict__ b2,
                         const int* __restrict__ seq_lens,
                         int* __restrict__ sel,
                         float* __restrict__ out_lens) {
    const int i = threadIdx.x;   // 64 threads = 1 wave
    __shared__ float e[64];
    const int L  = seq_lens[i];
    const int sl = ((L + 2) / 3 + 2) / 3;
    const float ei = (est_raw[i] + 228.0f * b2[0]) / (float)sl;  // = sum/sl
    e[i] = ei;
    __syncthreads();
    int rank = 0;
    for (int j = 0; j < 64; ++j) {
        float ej = e[j];
        rank += (ej > ei) || (ej == ei && j < i);
    }
    const bool selq = rank < NSEL;
    const unsigned long long m = __ballot(selq);
    if (selq) {
        int pos = __popcll(m & ((1ull << i) - 1ull));
        sel[pos] = i;
        out_lens[pos] = (float)L;
    }
}

// ---------------------------------------------------------------------------
__global__ __launch_bounds__(256) void gather_rows(const float* __restrict__ x,
                                                   const int* __restrict__ sel,
                                                   float* __restrict__ out,
                                                   int n4row) {
    const int i = blockIdx.y;
    const int v = blockIdx.x * 256 + threadIdx.x;
    if (v < n4row) {
        const int src = sel[i];
        const float4* xs = (const float4*)(x + (size_t)src * T_LEN * D_DIM);
        float4* od = (float4*)(out + (size_t)i * ((size_t)n4row * 4));
        od[v] = xs[v];
    }
}

// ---------------------------------------------------------------------------
extern "C" void kernel_launch(void* const* d_in, const int* in_sizes, int n_in,
                              void* d_out, int out_size, void* d_ws, size_t ws_size,
                              hipStream_t stream) {
    const float* x        = (const float*)d_in[0];
    const int*   seq_lens = (const int*)  d_in[1];
    const float* w1       = (const float*)d_in[2];
    const float* b1       = (const float*)d_in[3];
    const float* w2       = (const float*)d_in[4];
    const float* b2       = (const float*)d_in[5];
    float* out = (float*)d_out;

    char* ws = (char*)d_ws;
    unsigned short* whi = (unsigned short*)(ws + OFF_WHI);
    unsigned short* wlo = (unsigned short*)(ws + OFF_WLO);
    float* est_raw = (float*)(ws + OFF_EST);
    int*   sel     = (int*)  (ws + OFF_SEL);

    const int max_time = (out_size - NSEL) / (NSEL * D_DIM);

    pack_w1_split<<<768, 256, 0, stream>>>(w1, whi, wlo, est_raw);
    conv1_mfma<<<dim3(NTILES, B_SZ), 256, 0, stream>>>(x, whi, wlo, b1, w2, est_raw);
    select_k<<<1, 64, 0, stream>>>(est_raw, b2, seq_lens, sel,
                                   out + (size_t)NSEL * max_time * D_DIM);
    const int n4row = max_time * (D_DIM / 4);
    gather_rows<<<dim3((n4row + 255) / 256, NSEL), 256, 0, stream>>>(x, sel, out, n4row);
}